// Round 6
// baseline (530.625 us; speedup 1.0000x reference)
//
#include <hip/hip_runtime.h>

// 6-launch pipeline:
//   k_absmax3 (3 weight tensors -> 384 per-block partial maxes)
//   k_quant   (w0t f64 transpose-quant | w1r i8+sumr | fcr i8+sumfc, fused)
//   k_pool    (avg_pool 5x5 s3, f64 sums -> f32 [(b,p)][ic])
//   k_conv0   (f64 GEMM 6400x128x768 + bn0 + relu + actq -> i8 levels-128)
//   k_conv1f  (exact int GEMM 256x768x3200 + bn1 + relu + actq fused -> i8)
//   k_fcf     (exact int GEMM 256x1000x768 + scale + bias fused -> f32 out)
#define NB 256
#define NC 768
#define HW 289
#define NP 25
#define OC0 128
#define K1 3200
#define NO 1000

// ws offsets in BYTES
#define OFF_PM    0           // f32 [384] partial maxes (seg0:conv0_w seg1:conv1_w seg2:fc_w)
#define OFF_W0T   2048        // f64 [768][128]
#define OFF_POOL  788480      // f32 [6400][768]
#define OFF_A0K   20449280    // i8  [256][3200]
#define OFF_W1R   21268480    // i8  [768][3200]
#define OFF_SUMR1 23726080    // i32 [768]
#define OFF_A1K   23732224    // i8  [256][768]
#define OFF_FCR   23928832    // i8  [1000][768]
#define OFF_SUMFC 24696832    // i32 [1000]

#if __has_builtin(__builtin_amdgcn_sdot4)
__device__ __forceinline__ int DOT4(unsigned a, unsigned b, int c) {
    return __builtin_amdgcn_sdot4((int)a, (int)b, c, false);
}
#else
__device__ __forceinline__ int DOT4(unsigned a, unsigned b, int c) {
    #pragma unroll
    for (int q = 0; q < 4; ++q)
        c += (int)(char)(a >> (8*q)) * (int)(char)(b >> (8*q));
    return c;
}
#endif

// ---- fused absmax: 384 blocks, 128 per segment; per-block partial max ----
__global__ __launch_bounds__(256) void k_absmax3(const float* __restrict__ w0,
                                                 const float* __restrict__ w1,
                                                 const float* __restrict__ w2,
                                                 float* __restrict__ pmax) {
    int blk = blockIdx.x, seg = blk >> 7, lb = blk & 127;
    const float* w; int n;
    if (seg == 0)      { w = w0; n = 98304; }
    else if (seg == 1) { w = w1; n = 2457600; }
    else               { w = w2; n = 768000; }
    float m = 0.f;
    for (int i = lb * 256 + threadIdx.x; i < n; i += 128 * 256)
        m = fmaxf(m, fabsf(w[i]));
    #pragma unroll
    for (int off = 32; off; off >>= 1) m = fmaxf(m, __shfl_down(m, off));
    __shared__ float sm[4];
    if ((threadIdx.x & 63) == 0) sm[threadIdx.x >> 6] = m;
    __syncthreads();
    if (threadIdx.x == 0)
        pmax[blk] = fmaxf(fmaxf(sm[0], sm[1]), fmaxf(sm[2], sm[3]));
}

// all threads return the segment max (reduces the 128 partials)
__device__ __forceinline__ float seg_max(const float* __restrict__ pmax, int seg) {
    __shared__ float smax[4];
    float v = pmax[seg * 128 + (threadIdx.x & 127)];
    #pragma unroll
    for (int off = 32; off; off >>= 1) v = fmaxf(v, __shfl_down(v, off));
    if ((threadIdx.x & 63) == 0) smax[threadIdx.x >> 6] = v;
    __syncthreads();
    return fmaxf(fmaxf(smax[0], smax[1]), fmaxf(smax[2], smax[3]));
}

// ---- fused quant: blocks [0,96) w0t | [96,864) conv1 rows | [864,1864) fc rows ----
__global__ __launch_bounds__(256) void k_quant(const float* __restrict__ w0,
                                               const float* __restrict__ w1,
                                               const float* __restrict__ w2,
                                               const float* __restrict__ pmax,
                                               double* __restrict__ w0t,
                                               char* __restrict__ w1r, int* __restrict__ sumr1,
                                               char* __restrict__ fcr, int* __restrict__ sumfc) {
    int blk = blockIdx.x;
    if (blk < 96) {
        double scale = (double)seg_max(pmax, 0) / 127.0;
        #pragma unroll
        for (int l = 0; l < 4; ++l) {
            int i = blk * 1024 + l * 256 + threadIdx.x;    // 98304
            int ic = i >> 7, oc = i & 127;
            double r = rint((double)w0[oc * 768 + ic] / scale);
            r = fmin(fmax(r, -127.0), 127.0);
            w0t[i] = r * scale;
        }
        return;
    }
    const float* w; char* orow; int* sumr; int row, rowlen, seg;
    if (blk < 864) { seg = 1; row = blk - 96;  rowlen = K1; w = w1; orow = w1r + (size_t)row * K1; sumr = sumr1; }
    else           { seg = 2; row = blk - 864; rowlen = NC; w = w2; orow = fcr + (size_t)row * NC; sumr = sumfc; }
    double scale = (double)seg_max(pmax, seg) / 127.0;
    const float* wr = w + (size_t)row * rowlen;
    int s = 0;
    for (int t = threadIdx.x; t < rowlen; t += 256) {
        double r = rint((double)wr[t] / scale);
        r = fmin(fmax(r, -127.0), 127.0);
        int ri = (int)r;
        s += ri;
        orow[t] = (char)ri;
    }
    #pragma unroll
    for (int off = 32; off; off >>= 1) s += __shfl_down(s, off);
    __shared__ int sm[4];
    if ((threadIdx.x & 63) == 0) sm[threadIdx.x >> 6] = s;
    __syncthreads();
    if (threadIdx.x == 0) sumr[row] = sm[0] + sm[1] + sm[2] + sm[3];
}

// ---- avg_pool 5x5 s3 -> pool_t[(b*25+p)*768 + ic] f32 (f64 window sums) ----
__global__ __launch_bounds__(256) void k_pool(const float* __restrict__ x,
                                              float* __restrict__ pool_t) {
    __shared__ float tile[8 * HW];
    int g = blockIdx.x;                       // 24576 = 256 b * 96 icg
    int b = g / 96, icg = g % 96;
    const float* src = x + (size_t)g * (8 * HW);
    for (int i = threadIdx.x; i < 8 * HW; i += 256) tile[i] = src[i];
    __syncthreads();
    int t = threadIdx.x;
    if (t < 200) {
        int p = t >> 3, pl = t & 7;
        int oh = p / 5, ow = p % 5;
        const float* tp = tile + pl * HW + oh * 51 + ow * 3;
        double s = 0.0;
        #pragma unroll
        for (int kh = 0; kh < 5; ++kh)
            #pragma unroll
            for (int kw = 0; kw < 5; ++kw) s += (double)tp[kh * 17 + kw];
        pool_t[((size_t)b * NP + p) * NC + icg * 8 + pl] = (float)(s / 25.0);
    }
}

// ---- conv0: f64 GEMM C[6400x128] + bn0 + relu + actq -> a0k i8 ----
__global__ __launch_bounds__(256) void k_conv0(const float* __restrict__ A,
                                               const double* __restrict__ w0t,
                                               const float* __restrict__ g,
                                               const float* __restrict__ be,
                                               const float* __restrict__ mn,
                                               const float* __restrict__ vr,
                                               const float* __restrict__ alpha,
                                               char* __restrict__ a0k) {
    __shared__ double Ast[32][18];            // kk-major
    __shared__ double Bs[32][65];
    int m0 = blockIdx.x * 16;
    int oc0 = blockIdx.y * 64;
    int tid = threadIdx.x;
    int ty = tid >> 5, tx = tid & 31;
    double acc[2][2] = {};
    for (int k0 = 0; k0 < NC; k0 += 32) {
        {
            int r = tid >> 4, kk2 = (tid & 15) * 2;
            float2 v = *(const float2*)(A + (size_t)(m0 + r) * NC + k0 + kk2);
            Ast[kk2][r] = (double)v.x;
            Ast[kk2 + 1][r] = (double)v.y;
        }
        #pragma unroll
        for (int l = 0; l < 4; ++l) {
            int e = tid + l * 256;
            int r = e >> 5, c2 = (e & 31) * 2;
            double2 v = *(const double2*)(w0t + (size_t)(k0 + r) * OC0 + oc0 + c2);
            Bs[r][c2] = v.x; Bs[r][c2 + 1] = v.y;
        }
        __syncthreads();
        #pragma unroll
        for (int kk = 0; kk < 32; ++kk) {
            double av0 = Ast[kk][ty * 2], av1 = Ast[kk][ty * 2 + 1];
            double bv0 = Bs[kk][tx], bv1 = Bs[kk][tx + 32];
            acc[0][0] += av0 * bv0; acc[0][1] += av0 * bv1;
            acc[1][0] += av1 * bv0; acc[1][1] += av1 * bv1;
        }
        __syncthreads();
    }
    double a = (double)alpha[0];
    double s = a / 255.0;
    #pragma unroll
    for (int j = 0; j < 2; ++j) {
        int oc = oc0 + tx + 32 * j;
        double inv = (double)g[oc] / sqrt((double)vr[oc] + 1e-3);
        double sh = (double)be[oc] - (double)mn[oc] * inv;
        #pragma unroll
        for (int i = 0; i < 2; ++i) {
            int m = m0 + ty * 2 + i;
            int b = m / 25, p = m % 25;
            double y = acc[i][j] * inv + sh;
            y = fmax(y, 0.0); y = fmin(y, a);
            int k = (int)rint(y / s);
            a0k[(size_t)b * K1 + oc * 25 + p] = (char)(k - 128);
        }
    }
}

// ---- conv1 fused: int GEMM 256x768x3200 + bn1 + relu + actq -> a1k i8 ----
__global__ __launch_bounds__(256) void k_conv1f(const char* __restrict__ a0k,
                                                const char* __restrict__ w1r,
                                                const int* __restrict__ sumr,
                                                const float* __restrict__ g,
                                                const float* __restrict__ be,
                                                const float* __restrict__ mn,
                                                const float* __restrict__ vr,
                                                const float* __restrict__ alpha0,
                                                const float* __restrict__ alpha1,
                                                const float* __restrict__ pmax,
                                                char* __restrict__ a1k) {
    __shared__ unsigned As[16][17];
    __shared__ unsigned Bs[16][17];
    int b0 = blockIdx.x * 16, oc0 = blockIdx.y * 16;
    int tid = threadIdx.x;
    int ty = tid >> 4, tx = tid & 15;
    float mx1 = seg_max(pmax, 1);
    int acc = 0;
    for (int k0 = 0; k0 < K1; k0 += 64) {
        As[ty][tx] = *(const unsigned*)(a0k + (size_t)(b0 + ty) * K1 + k0 + tx * 4);
        Bs[ty][tx] = *(const unsigned*)(w1r + (size_t)(oc0 + ty) * K1 + k0 + tx * 4);
        __syncthreads();
        #pragma unroll
        for (int kd = 0; kd < 16; ++kd)
            acc = DOT4(As[ty][kd], Bs[tx][kd], acc);
        __syncthreads();
    }
    int oc = oc0 + tx;
    int s = acc + 128 * sumr[oc];
    double m = ((double)alpha0[0] / 255.0) * ((double)mx1 / 127.0);
    double inv = (double)g[oc] / sqrt((double)vr[oc] + 1e-3);
    double sh = (double)be[oc] - (double)mn[oc] * inv;
    double a = (double)alpha1[0];
    double s1 = a / 255.0;
    double y = (double)s * m * inv + sh;
    y = fmax(y, 0.0); y = fmin(y, a);
    int k = (int)rint(y / s1);
    a1k[(size_t)(b0 + ty) * NC + oc] = (char)(k - 128);
}

// ---- fc fused: int GEMM 256x1000x768 + scale + bias -> f32 out ----
__global__ __launch_bounds__(256) void k_fcf(const char* __restrict__ a1k,
                                             const char* __restrict__ fcr,
                                             const int* __restrict__ sumr,
                                             const float* __restrict__ alpha1,
                                             const float* __restrict__ pmax,
                                             const float* __restrict__ bias,
                                             float* __restrict__ out) {
    __shared__ unsigned As[16][17];
    __shared__ unsigned Bs[64][17];
    int b0 = blockIdx.x * 16, o0 = blockIdx.y * 64;
    int tid = threadIdx.x;
    int ty = tid >> 4, tx = tid & 15;
    float mx2 = seg_max(pmax, 2);
    int acc[4] = {};
    for (int k0 = 0; k0 < NC; k0 += 64) {
        As[ty][tx] = *(const unsigned*)(a1k + (size_t)(b0 + ty) * NC + k0 + tx * 4);
        {
            int row = tid >> 2, c4 = (tid & 3) * 4;
            uint4 v = make_uint4(0u, 0u, 0u, 0u);
            if (o0 + row < NO)
                v = *(const uint4*)(fcr + (size_t)(o0 + row) * NC + k0 + c4 * 4);
            Bs[row][c4] = v.x; Bs[row][c4 + 1] = v.y;
            Bs[row][c4 + 2] = v.z; Bs[row][c4 + 3] = v.w;
        }
        __syncthreads();
        #pragma unroll
        for (int kd = 0; kd < 16; ++kd) {
            unsigned av = As[ty][kd];
            #pragma unroll
            for (int j = 0; j < 4; ++j)
                acc[j] = DOT4(av, Bs[tx + 16 * j][kd], acc[j]);
        }
        __syncthreads();
    }
    double m = ((double)alpha1[0] / 255.0) * ((double)mx2 / 127.0);
    #pragma unroll
    for (int j = 0; j < 4; ++j) {
        int o = o0 + tx + 16 * j;
        if (o < NO) {
            int s = acc[j] + 128 * sumr[o];
            out[(size_t)(b0 + ty) * NO + o] = (float)((double)s * m + (double)bias[o]);
        }
    }
}

extern "C" void kernel_launch(void* const* d_in, const int* in_sizes, int n_in,
                              void* d_out, int out_size, void* d_ws, size_t ws_size,
                              hipStream_t stream) {
    const float* act     = (const float*)d_in[0];
    const float* conv0_w = (const float*)d_in[2];
    const float* bn0g = (const float*)d_in[3];
    const float* bn0b = (const float*)d_in[4];
    const float* bn0m = (const float*)d_in[5];
    const float* bn0v = (const float*)d_in[6];
    const float* alpha0 = (const float*)d_in[7];
    const float* conv1_w = (const float*)d_in[8];
    const float* bn1g = (const float*)d_in[9];
    const float* bn1b = (const float*)d_in[10];
    const float* bn1m = (const float*)d_in[11];
    const float* bn1v = (const float*)d_in[12];
    const float* alpha1 = (const float*)d_in[13];
    const float* fc_w = (const float*)d_in[14];
    const float* fc_b = (const float*)d_in[15];

    char* base = (char*)d_ws;
    float* pmax  = (float*)(base + OFF_PM);
    double* w0t  = (double*)(base + OFF_W0T);
    float* poolt = (float*)(base + OFF_POOL);
    char* a0k    = (char*)(base + OFF_A0K);
    char* w1r    = (char*)(base + OFF_W1R);
    int* sumr1   = (int*)(base + OFF_SUMR1);
    char* a1k    = (char*)(base + OFF_A1K);
    char* fcr    = (char*)(base + OFF_FCR);
    int* sumfc   = (int*)(base + OFF_SUMFC);
    float* out   = (float*)d_out;

    k_absmax3<<<384, 256, 0, stream>>>(conv0_w, conv1_w, fc_w, pmax);
    k_quant<<<1864, 256, 0, stream>>>(conv0_w, conv1_w, fc_w, pmax,
                                      w0t, w1r, sumr1, fcr, sumfc);
    k_pool<<<24576, 256, 0, stream>>>(act, poolt);
    k_conv0<<<dim3(400, 2), 256, 0, stream>>>(poolt, w0t, bn0g, bn0b, bn0m, bn0v,
                                              alpha0, a0k);
    k_conv1f<<<dim3(16, 48), 256, 0, stream>>>(a0k, w1r, sumr1, bn1g, bn1b, bn1m, bn1v,
                                               alpha0, alpha1, pmax, a1k);
    k_fcf<<<dim3(16, 16), 256, 0, stream>>>(a1k, fcr, sumfc, alpha1, pmax, fc_b, out);
}